// Round 1
// 504.201 us; speedup vs baseline: 1.0267x; 1.0267x over previous
//
#include <hip/hip_runtime.h>
#include <math.h>

#define B_ 16
#define C_ 256
#define H_ 128
#define W_ 128
#define HW_ (H_*W_)
#define PO 20
#define NPOOL (PO*PO)
#define MID_ 16
#define OC_ 32
#define OH_ 64
#define OW_ 64
#define BN_EPS 1e-3f

// workspace offsets in floats
#define OFF_XP     0
#define OFF_SN     1638400
#define OFF_SCORE  1648896
#define OFF_BNSUM  1649184
#define OFF_BNSQ   1649216
#define OFF_SMEAN  1649248
#define OFF_SMAX   1911392
#define OFF_SIGA   2173536
#define OFF_XC     2435680

// adaptive-pool bin start/end for n=128 -> 20 (H and W identical)
__device__ __forceinline__ int bin_s(int p) { return (p * 128) / 20; }
__device__ __forceinline__ int bin_e(int p) { return ((p + 1) * 128 + 19) / 20; }

// ---------------- 1. fused pool + group-mean + column-sum -------------------
// Aligned 32-col chunks share the relative bin pattern S={0,6,12,19,25},
// E={7,13,20,26,32}. Block=(b, group g, row-half rh). Thread=(row hl, col q).
// NEW vs prev: (a) channel k+1 is prefetched into registers BEFORE the
// barrier; (b) the barrier is raw s_barrier with lgkmcnt(0) only -- no
// vmcnt(0) drain, so the prefetch stays in flight across the barrier.
// Safety: only LDS tmp crosses the barrier (lgkm-drained); the in-flight
// global loads target private registers. xp stores / sn atomics have no
// in-kernel readers.
__global__ __launch_bounds__(256) void k_pool2(const float* __restrict__ x,
                                               float* __restrict__ xp,
                                               float* __restrict__ sn,
                                               float* __restrict__ xc) {
  __shared__ float tmp[2][64 * 21]; // 10.5 KB, double-buffered
  const int blk = blockIdx.x;
  const int b = blk >> 5, g = (blk >> 1) & 15, rh = blk & 1;
  const int tid = threadIdx.x;
  const int hl = tid >> 2, q = tid & 3;
  const int hg = rh * 64 + hl;
  const float* rowbase = x + (size_t)(b * C_) * HW_ + (size_t)hg * W_ + q * 32;

  float4 xacc[8];
#pragma unroll
  for (int j = 0; j < 8; ++j) xacc[j] = make_float4(0.f, 0.f, 0.f, 0.f);
  float snacc = 0.f;

  float4 cur[8], nxt[8];
  {
    const float4* s4 = (const float4*)(rowbase + (size_t)(g * 16) * HW_);
#pragma unroll
    for (int j = 0; j < 8; ++j) cur[j] = s4[j];
  }

#pragma unroll
  for (int k = 0; k < 16; ++k) {
    // prefetch next channel (stays outstanding across the raw barrier)
    if (k < 15) {
      const float4* s4 = (const float4*)(rowbase + (size_t)(g * 16 + k + 1) * HW_);
#pragma unroll
      for (int j = 0; j < 8; ++j) nxt[j] = s4[j];
    }
    const int c = g * 16 + k;
    float bin[5];
#pragma unroll
    for (int p = 0; p < 5; ++p) bin[p] = 0.f;
#pragma unroll
    for (int j = 0; j < 8; ++j) {
      float4 v = cur[j];
      xacc[j].x += v.x; xacc[j].y += v.y; xacc[j].z += v.z; xacc[j].w += v.w;
      const float c4[4] = {v.x, v.y, v.z, v.w};
#pragma unroll
      for (int kk = 0; kk < 4; ++kk) {
        const int cc = 4 * j + kk;
#pragma unroll
        for (int p = 0; p < 5; ++p) {
          const int S = (p * 32) / 5;            // 0,6,12,19,25
          const int E = ((p + 1) * 32 + 4) / 5;  // 7,13,20,26,32
          if (cc >= S && cc < E) bin[p] += c4[kk]; // folds at compile time
        }
      }
    }
    float* tb = tmp[k & 1];
#pragma unroll
    for (int p = 0; p < 5; ++p) {
      const int S = (p * 32) / 5, E = ((p + 1) * 32 + 4) / 5;
      tb[hl * 21 + q * 5 + p] = bin[p] / (float)(E - S);
    }
    // raw barrier: drain LDS only, keep global prefetch in flight
    asm volatile("s_waitcnt lgkmcnt(0)\n\ts_barrier" ::: "memory");
    if (tid < 200) { // 10 output rows x 20 cols for this channel
      const int ol = tid / 20, p = tid % 20;
      const int o = rh * 10 + ol;
      const int rs_ = bin_s(o), re_ = bin_e(o);
      float s = 0.f;
      for (int r = rs_; r < re_; ++r) s += tb[(r - rh * 64) * 21 + p];
      float v = s / (float)(re_ - rs_);
      xp[(size_t)(b * C_ + c) * NPOOL + o * PO + p] = v;
      snacc += v;
    }
    // no second barrier: next iter writes tmp[(k+1)&1]; buffer reuse (k+2)
    // is separated from these reads by barrier k+1 (reads lgkm-drained there).
    if (k < 15) {
#pragma unroll
      for (int j = 0; j < 8; ++j) cur[j] = nxt[j];
    }
  }
  if (tid < 200) atomicAdd(&sn[b * NPOOL + rh * 200 + tid], snacc);
  // group-mean channel -> xc[b][16+g]
  float4* dst = (float4*)(xc + (size_t)(b * OC_ + MID_ + g) * HW_ + (size_t)hg * W_ + q * 32);
#pragma unroll
  for (int j = 0; j < 8; ++j) {
    float4 v = xacc[j];
    v.x *= 0.0625f; v.y *= 0.0625f; v.z *= 0.0625f; v.w *= 0.0625f;
    dst[j] = v;
  }
}

// ---------------- 2. fused feat + attn + score ------------------------------
// feat[b,i] = (dot_i - totm*rs_i) / (399*256), with
//   rs_i = sum_n xp[i,n], dot_i = sum_n xp[i,n]*sn[n], totm = (sum_c rs_c)/400.
// (The old 'S' term is analytically zero: S = sum_n sn - 400*totm == 0.)
// Then attn z_j = feat . lw[j,:] + lb[j]; score[j] += sigmoid(z_j)/16.
// Single pass over xp, feat stays in LDS, one dispatch instead of two.
__global__ __launch_bounds__(256) void k_featattn(const float* __restrict__ xp,
                                                  const float* __restrict__ sn,
                                                  const float* __restrict__ lw,
                                                  const float* __restrict__ lb,
                                                  float* __restrict__ score) {
  const int b = blockIdx.x;
  const int tid = threadIdx.x;
  __shared__ float snl[NPOOL];
  __shared__ float red[256];
  __shared__ float featl[C_];
  for (int i = tid; i < NPOOL; i += 256) snl[i] = sn[b * NPOOL + i];
  __syncthreads();
  const float4* row4 = (const float4*)(xp + (size_t)(b * C_ + tid) * NPOOL);
  float rs = 0.f, dot = 0.f;
#pragma unroll 4
  for (int n = 0; n < NPOOL / 4; ++n) {
    float4 v = row4[n];
    rs += v.x + v.y + v.z + v.w;
    dot += v.x * snl[4 * n] + v.y * snl[4 * n + 1]
         + v.z * snl[4 * n + 2] + v.w * snl[4 * n + 3];
  }
  red[tid] = rs;
  __syncthreads();
  for (int s = 128; s > 0; s >>= 1) {
    if (tid < s) red[tid] += red[tid + s];
    __syncthreads();
  }
  const float totm = red[0] / (float)NPOOL; // sum_c mean_c
  featl[tid] = (dot - totm * rs) / ((float)(NPOOL - 1) * (float)C_);
  __syncthreads();
  // attn row for this b: thread j computes z_j (featl reads are broadcast)
  const float4* wrow = (const float4*)(lw + (size_t)tid * C_);
  float z = 0.f;
#pragma unroll 4
  for (int i = 0; i < C_ / 4; ++i) {
    float4 w = wrow[i];
    z += w.x * featl[4 * i] + w.y * featl[4 * i + 1]
       + w.z * featl[4 * i + 2] + w.w * featl[4 * i + 3];
  }
  z += lb[tid];
  float sig = 1.0f / (1.0f + expf(-z)); // accurate expf: score gaps ~1e-6
  atomicAdd(&score[tid], sig * (1.0f / (float)B_));
}

// ---------------- 3. build xc[0..15] + channel mean/max (select inlined) ----
// Stable top-16 (desc, ties by index) recomputed redundantly per block from
// score[] -- removes the single-block k_select dispatch bubble.
__global__ __launch_bounds__(256) void k_build(const float* __restrict__ x,
                                               const float* __restrict__ score,
                                               float* __restrict__ xc,
                                               float* __restrict__ smean,
                                               float* __restrict__ smax) {
  __shared__ float ss[C_];
  __shared__ int flag[C_];
  __shared__ int mid_s[MID_];
  __shared__ float sc_s[MID_];
  __shared__ float4 ps[128], pm[128];
  const int tid = threadIdx.x;
  ss[tid] = score[tid];
  __syncthreads();
  {
    float my = ss[tid];
    int rank = 0;
    for (int k = 0; k < C_; ++k) {
      float v = ss[k];
      rank += (v > my || (v == my && k < tid)) ? 1 : 0;
    }
    flag[tid] = (rank < MID_) ? 1 : 0;
    __syncthreads();
    if (rank < MID_) {
      int pos = 0;
      for (int k = 0; k < tid; ++k) pos += flag[k];
      mid_s[pos] = tid;       // ascending channel order == jnp.sort
      sc_s[pos] = 1.0f + my;
    }
  }
  __syncthreads();
  const int p = tid & 127, s = tid >> 7;
  const int P = blockIdx.x * 128 + p; // over B*HW/4 = 65536
  const int b = P >> 12, pix4 = P & 4095;
  const float4* xb = (const float4*)x + (size_t)(b * C_) * (HW_ / 4) + pix4;
  float4* xcb = (float4*)xc + (size_t)(b * OC_) * (HW_ / 4) + pix4;
  float4 ms = make_float4(0.f, 0.f, 0.f, 0.f);
  float4 mx = make_float4(-INFINITY, -INFINITY, -INFINITY, -INFINITY);
#pragma unroll
  for (int mi = 0; mi < 8; ++mi) {
    int m = s * 8 + mi;
    float4 t = xb[(size_t)mid_s[m] * (HW_ / 4)];
    float sc = sc_s[m];
    t.x *= sc; t.y *= sc; t.z *= sc; t.w *= sc;
    xcb[(size_t)m * (HW_ / 4)] = t;
    ms.x += t.x; ms.y += t.y; ms.z += t.z; ms.w += t.w;
    mx.x = fmaxf(mx.x, t.x); mx.y = fmaxf(mx.y, t.y);
    mx.z = fmaxf(mx.z, t.z); mx.w = fmaxf(mx.w, t.w);
  }
#pragma unroll
  for (int gi = 0; gi < 8; ++gi) {
    float4 t = xcb[(size_t)(MID_ + s * 8 + gi) * (HW_ / 4)];
    ms.x += t.x; ms.y += t.y; ms.z += t.z; ms.w += t.w;
    mx.x = fmaxf(mx.x, t.x); mx.y = fmaxf(mx.y, t.y);
    mx.z = fmaxf(mx.z, t.z); mx.w = fmaxf(mx.w, t.w);
  }
  if (s == 1) { ps[p] = ms; pm[p] = mx; }
  __syncthreads();
  if (s == 0) {
    float4 a = ps[p], m2 = pm[p];
    ms.x = (ms.x + a.x) * (1.f / 32.f); ms.y = (ms.y + a.y) * (1.f / 32.f);
    ms.z = (ms.z + a.z) * (1.f / 32.f); ms.w = (ms.w + a.w) * (1.f / 32.f);
    mx.x = fmaxf(mx.x, m2.x); mx.y = fmaxf(mx.y, m2.y);
    mx.z = fmaxf(mx.z, m2.z); mx.w = fmaxf(mx.w, m2.w);
    ((float4*)smean)[P] = ms;
    ((float4*)smax)[P] = mx;
  }
}

// ---------------- 4. LSA 7x7 conv (2->1) pad 3 + sigmoid ------------------
__global__ __launch_bounds__(256) void k_lsa(const float* __restrict__ smean,
                                             const float* __restrict__ smax,
                                             const float* __restrict__ lsa_w,
                                             float* __restrict__ siga) {
  __shared__ float w0[49], w1[49];
  if (threadIdx.x < 49) {
    w0[threadIdx.x] = lsa_w[threadIdx.x];
    w1[threadIdx.x] = lsa_w[49 + threadIdx.x];
  }
  __syncthreads();
  int idx = blockIdx.x * 256 + threadIdx.x; // over B*HW
  int b = idx >> 14;
  int pix = idx & (HW_ - 1);
  int h = pix >> 7, w = pix & 127;
  const float* pm = smean + (size_t)b * HW_;
  const float* px = smax + (size_t)b * HW_;
  float acc = 0.f;
  for (int kh = 0; kh < 7; ++kh) {
    int ih = h + kh - 3;
    if (ih < 0 || ih >= H_) continue;
    for (int kw = 0; kw < 7; ++kw) {
      int iw = w + kw - 3;
      if (iw < 0 || iw >= W_) continue;
      int p = ih * W_ + iw;
      acc += pm[p] * w0[kh * 7 + kw] + px[p] * w1[kh * 7 + kw];
    }
  }
  siga[idx] = 1.0f / (1.0f + __expf(-acc));
}

// ---------------- 5. conv 3x3 stride2 pad1 (32->32) + bias + BN partials ---
// NEW vs prev: w_lds stride 33 (staging writes were a 64-way bank conflict
// at stride 32: bank = (rem*32+oc)%32 = oc const over the i-loop); 9 weights
// per (icl) hoisted to registers (scalar LDS reads 960 -> 288 per thread).
__global__ __launch_bounds__(256) void k_conv(const float* __restrict__ xc,
                                              const float* __restrict__ siga,
                                              const float* __restrict__ conv_w,
                                              const float* __restrict__ conv_b,
                                              float* __restrict__ out,
                                              float* __restrict__ bnsum,
                                              float* __restrict__ bnsq) {
  __shared__ __attribute__((aligned(16))) float in_lds[4 * 5 * 132]; // 10.6 KB
  __shared__ float sg_lds[5 * 132];                                  // 2.6 KB
  __shared__ float w_lds[288 * 33];                                  // 38 KB
  const int tid = threadIdx.x;
  const int oc = tid & 31;
  const int g = tid >> 5;
  const int b = blockIdx.x >> 5;
  const int oh0 = (blockIdx.x & 31) * 2;
  const int ih0 = 2 * oh0 - 1; // rows ih0..ih0+4

  for (int i = tid; i < 288 * 32; i += 256) {
    int oc_ = i / 288, rem = i % 288;
    w_lds[rem * 33 + oc_] = conv_w[i]; // banks (rem+oc_)%32: conflict-free
  }
  const float* sgb = siga + (size_t)b * HW_;
  for (int i = tid; i < 5 * 132; i += 256) {
    int r = i / 132, col = i % 132;
    int ih = ih0 + r, iw = col - 1;
    float v = 0.f;
    if (ih >= 0 && ih < H_ && iw >= 0 && iw < W_) v = sgb[ih * W_ + iw];
    sg_lds[i] = v;
  }

  float acc[2][8];
#pragma unroll
  for (int a = 0; a < 2; ++a)
#pragma unroll
    for (int o = 0; o < 8; ++o) acc[a][o] = 0.f;

  for (int chunk = 0; chunk < 8; ++chunk) {
    __syncthreads();
    for (int i = tid; i < 4 * 5 * 132; i += 256) {
      int icl = i / 660;
      int rem = i % 660;
      int r = rem / 132, col = rem % 132;
      int ih = ih0 + r, iw = col - 1;
      float v = 0.f;
      if (ih >= 0 && ih < H_ && iw >= 0 && iw < W_) {
        v = xc[((size_t)(b * OC_) + (chunk * 4 + icl)) * HW_ + ih * W_ + iw] * sg_lds[rem];
      }
      in_lds[i] = v;
    }
    __syncthreads();
#pragma unroll
    for (int icl = 0; icl < 4; ++icl) {
      float wr[9];
      const int wb = (chunk * 4 + icl) * 9 * 33 + oc;
#pragma unroll
      for (int t = 0; t < 9; ++t) wr[t] = w_lds[wb + t * 33];
#pragma unroll
      for (int r = 0; r < 5; ++r) {
        float f[20] __attribute__((aligned(16)));
        const float4* s4 = (const float4*)&in_lds[(icl * 5 + r) * 132 + 16 * g];
#pragma unroll
        for (int j = 0; j < 5; ++j) ((float4*)f)[j] = s4[j];
#pragma unroll
        for (int ohl = 0; ohl < 2; ++ohl) {
          const int kh = r - 2 * ohl;
          if (kh < 0 || kh > 2) continue; // compile-time after unroll
          float w0 = wr[kh * 3 + 0];
          float w1 = wr[kh * 3 + 1];
          float w2 = wr[kh * 3 + 2];
#pragma unroll
          for (int o = 0; o < 8; ++o)
            acc[ohl][o] += f[2 * o] * w0 + f[2 * o + 1] * w1 + f[2 * o + 2] * w2;
        }
      }
    }
  }

  float bias = conv_b[oc];
  float lsum = 0.f, lsq = 0.f;
  float* outp = out + ((size_t)(b * OC_) + oc) * (OH_ * OW_) + (size_t)oh0 * OW_ + g * 8;
#pragma unroll
  for (int ohl = 0; ohl < 2; ++ohl) {
    float vout[8] __attribute__((aligned(16)));
#pragma unroll
    for (int o = 0; o < 8; ++o) {
      float v = acc[ohl][o] + bias;
      vout[o] = v;
      lsum += v;
      lsq += v * v;
    }
    *((float4*)(outp + ohl * OW_)) = *(float4*)&vout[0];
    *((float4*)(outp + ohl * OW_ + 4)) = *(float4*)&vout[4];
  }
  __syncthreads(); // done reading in_lds; reuse for reduction
  in_lds[tid] = lsum;
  in_lds[256 + tid] = lsq;
  __syncthreads();
  if (tid < 32) {
    float t = 0.f, tq = 0.f;
#pragma unroll
    for (int gg = 0; gg < 8; ++gg) {
      t += in_lds[gg * 32 + tid];
      tq += in_lds[256 + gg * 32 + tid];
    }
    atomicAdd(&bnsum[tid], t);
    atomicAdd(&bnsq[tid], tq);
  }
}

// ---------------- 6. BN finalize (redundant per block) + apply + SiLU ------
__global__ __launch_bounds__(256) void k_apply(float* __restrict__ out,
                                               const float* __restrict__ sum,
                                               const float* __restrict__ sq,
                                               const float* __restrict__ gamma,
                                               const float* __restrict__ beta) {
  __shared__ float ssc[OC_], ssh[OC_];
  if (threadIdx.x < OC_) {
    int i = threadIdx.x;
    const float N = (float)(B_ * OH_ * OW_);
    float mu = sum[i] / N;
    float var = sq[i] / N - mu * mu; // population var (ddof=0)
    float sc = gamma[i] / sqrtf(var + BN_EPS);
    ssc[i] = sc;
    ssh[i] = beta[i] - mu * sc;
  }
  __syncthreads();
  int idx4 = blockIdx.x * 256 + threadIdx.x; // over out_size/4 = 524288
  int oc = (idx4 >> 10) & 31;                // 1024 float4 per (b,oc) plane
  float sc = ssc[oc], sh = ssh[oc];
  float4 v = ((float4*)out)[idx4];
  float t;
  t = v.x * sc + sh; v.x = t / (1.0f + __expf(-t));
  t = v.y * sc + sh; v.y = t / (1.0f + __expf(-t));
  t = v.z * sc + sh; v.z = t / (1.0f + __expf(-t));
  t = v.w * sc + sh; v.w = t / (1.0f + __expf(-t));
  ((float4*)out)[idx4] = v;
}

extern "C" void kernel_launch(void* const* d_in, const int* in_sizes, int n_in,
                              void* d_out, int out_size, void* d_ws, size_t ws_size,
                              hipStream_t stream) {
  const float* x      = (const float*)d_in[0];
  const float* lw     = (const float*)d_in[1];
  const float* lb     = (const float*)d_in[2];
  const float* lsa_w  = (const float*)d_in[3];
  const float* conv_w = (const float*)d_in[4];
  const float* conv_b = (const float*)d_in[5];
  const float* gamma  = (const float*)d_in[6];
  const float* beta   = (const float*)d_in[7];
  float* out = (float*)d_out;
  float* ws = (float*)d_ws;

  // one contiguous clear: sn + (gap) + score + bnsum + bnsq
  hipMemsetAsync(ws + OFF_SN, 0,
                 (size_t)(OFF_BNSQ + OC_ - OFF_SN) * sizeof(float), stream);

  k_pool2<<<512, 256, 0, stream>>>(x, ws + OFF_XP, ws + OFF_SN, ws + OFF_XC);
  k_featattn<<<B_, 256, 0, stream>>>(ws + OFF_XP, ws + OFF_SN, lw, lb, ws + OFF_SCORE);
  k_build<<<512, 256, 0, stream>>>(x, ws + OFF_SCORE, ws + OFF_XC,
                                   ws + OFF_SMEAN, ws + OFF_SMAX);
  k_lsa<<<1024, 256, 0, stream>>>(ws + OFF_SMEAN, ws + OFF_SMAX, lsa_w, ws + OFF_SIGA);
  k_conv<<<512, 256, 0, stream>>>(ws + OFF_XC, ws + OFF_SIGA, conv_w, conv_b, out,
                                  ws + OFF_BNSUM, ws + OFF_BNSQ);
  k_apply<<<2048, 256, 0, stream>>>(out, ws + OFF_BNSUM, ws + OFF_BNSQ, gamma, beta);
}